// Round 15
// baseline (69.327 us; speedup 1.0000x reference)
//
#include <hip/hip_runtime.h>
#include <hip/hip_bf16.h>
#include <math.h>

#define N_NODES 10000
#define MPAD    10112      // 79 * 128
#define N_EDGES 320000
#define NFEAT   512
#define NHID    256
#define NCLASS  40
#define SLOT    96         // max deg bound: Binom(320K,1e-4) max ~55; P(>96) ~ 0
#define CSTRIDE 16         // one counter per 64B line
#define NBM1    158        // gemm1 m-tiles (64 rows each), BN=256 full width
#define EB2     ((N_EDGES + 511) / 512)   // 625 scatter blocks (512 thr)

typedef short  short8  __attribute__((ext_vector_type(8)));
typedef float  floatx4 __attribute__((ext_vector_type(4)));

__device__ __forceinline__ unsigned short f2b(float f) {
  __hip_bfloat16 h = __float2bfloat16(f);
  unsigned short u; __builtin_memcpy(&u, &h, 2); return u;
}
__device__ __forceinline__ float b2f(unsigned short u) {
  return __uint_as_float(((unsigned)u) << 16);
}
__device__ __forceinline__ short8 pack8(float4 a, float4 b) {
  short8 r;
  r[0] = (short)f2b(a.x); r[1] = (short)f2b(a.y); r[2] = (short)f2b(a.z); r[3] = (short)f2b(a.w);
  r[4] = (short)f2b(b.x); r[5] = (short)f2b(b.y); r[6] = (short)f2b(b.z); r[7] = (short)f2b(b.w);
  return r;
}

// ---------------- prep: W1->bf16 transposed, W2->bf16 transposed+padded,
//                  cnt (padded) -> 0 ----------------

__global__ __launch_bounds__(256) void prep_k(const float* __restrict__ W1,
                                              const float* __restrict__ W2,
                                              unsigned short* __restrict__ w1t,
                                              unsigned short* __restrict__ w2t,
                                              int* __restrict__ cnt) {
  int tid = blockIdx.x * 256 + threadIdx.x;
  if (tid < N_NODES * CSTRIDE) cnt[tid] = 0;
  const int nw1 = NFEAT * NHID;              // 131,072
  if (tid < nw1) {
    int k = tid / NHID, n = tid % NHID;        // coalesced read of W1
    w1t[n * NFEAT + k] = f2b(W1[tid]);         // transposed bf16 write
  } else if (tid < nw1 + 64 * NHID) {
    int j = tid - nw1;
    int n = j >> 8;                            // out-col 0..63
    int k = j & 255;                           // k 0..255
    w2t[j] = (n < NCLASS) ? f2b(W2[k * NCLASS + n]) : (unsigned short)0;
  }
}

// ---------------- fused: GEMM1 64x256 dbuf (blocks < NBM1)  ||  slot-scatter ----------------
// 512 threads. gemm1: 8 waves, each 64x32 cols (acc[4][2]); A staged from f32 x
// (read once from HBM), B = w1t rows (L2-hot). Scatter: 625 blocks x 512 edges.

__global__ __launch_bounds__(512) void gemm1_scatter_k(
    const float* __restrict__ x, const unsigned short* __restrict__ w1t,
    unsigned short* __restrict__ xw1b,
    const int* __restrict__ src, const int* __restrict__ dst,
    const float* __restrict__ w, int* __restrict__ cnt, int2* __restrict__ epk) {
  if (blockIdx.x >= NBM1) {
    int e = (blockIdx.x - NBM1) * 512 + threadIdx.x;
    if (e < N_EDGES) {
      int d = dst[e];
      int p = atomicAdd(&cnt[d << 4], 1);
      int2 pk; pk.x = src[e]; pk.y = __float_as_int(w[e]);
      epk[d * SLOT + p] = pk;
    }
    return;
  }

  __shared__ short8 As[2][64 * 4];     // 8 KB
  __shared__ short8 Bs[2][256 * 4];    // 32 KB

  const int t  = threadIdx.x;
  const int l  = t & 63;
  const int wc = t >> 6;                    // wave 0..7 -> col strip of 32
  const int bm = blockIdx.x * 64;

  // staging roles: threads 0..255 -> A, 256..511 -> B
  const bool  isA  = (t < 256);
  const int   rowA = t >> 2, sA = t & 3;    // A: 8 f32 -> 1 short8 slot
  const int   rowB = t - 256;               // B: full w1t row, 4 short8 slots

  const float4 z4 = make_float4(0.f, 0.f, 0.f, 0.f);
  const floatx4 zero = {0.f, 0.f, 0.f, 0.f};
  floatx4 acc[4][2];
#pragma unroll
  for (int mi = 0; mi < 4; mi++) { acc[mi][0] = zero; acc[mi][1] = zero; }

  const int q = l >> 4;
  const bool arok = isA && ((bm + rowA) < N_NODES);
  const float* xrow = &x[(size_t)(bm + rowA) * NFEAT + sA * 8];
  const unsigned short* brow = &w1t[(size_t)rowB * NFEAT];

  // prologue: stage k0 = 0 into buffer 0
  if (isA) {
    float4 a0 = z4, a1 = z4;
    if (arok) { a0 = *(const float4*)(xrow); a1 = *(const float4*)(xrow + 4); }
    As[0][rowA * 4 + (sA ^ (rowA & 3))] = pack8(a0, a1);
  } else {
#pragma unroll
    for (int s = 0; s < 4; s++)
      Bs[0][rowB * 4 + (s ^ (rowB & 3))] = *(const short8*)(brow + s * 8);
  }

  for (int s = 0; s < 16; s++) {
    __syncthreads();                      // buf[s&1] staged; prior readers done
    const int cur = s & 1;
    float4 na0 = z4, na1 = z4;
    short8 nb[4];
    const bool more = (s < 15);
    if (more) {
      const int k1 = (s + 1) * 32;
      if (isA) {
        if (arok) { na0 = *(const float4*)(xrow + k1); na1 = *(const float4*)(xrow + k1 + 4); }
      } else {
#pragma unroll
        for (int ss = 0; ss < 4; ss++) nb[ss] = *(const short8*)(brow + k1 + ss * 8);
      }
    }

    short8 af[4], bf[2];
#pragma unroll
    for (int mi = 0; mi < 4; mi++) {
      int ar = mi * 16 + (l & 15);
      af[mi] = As[cur][ar * 4 + (q ^ (ar & 3))];
    }
#pragma unroll
    for (int ni = 0; ni < 2; ni++) {
      int bc = wc * 32 + ni * 16 + (l & 15);
      bf[ni] = Bs[cur][bc * 4 + (q ^ (bc & 3))];
    }
#pragma unroll
    for (int mi = 0; mi < 4; mi++)
#pragma unroll
      for (int ni = 0; ni < 2; ni++)
        acc[mi][ni] = __builtin_amdgcn_mfma_f32_16x16x32_bf16(af[mi], bf[ni], acc[mi][ni], 0, 0, 0);

    if (more) {
      const int nxt = cur ^ 1;
      if (isA) {
        As[nxt][rowA * 4 + (sA ^ (rowA & 3))] = pack8(na0, na1);
      } else {
#pragma unroll
        for (int ss = 0; ss < 4; ss++)
          Bs[nxt][rowB * 4 + (ss ^ (rowB & 3))] = nb[ss];
      }
    }
  }

#pragma unroll
  for (int mi = 0; mi < 4; mi++)
#pragma unroll
    for (int ni = 0; ni < 2; ni++) {
      int row = bm + mi * 16 + (l >> 4) * 4;
      int col = wc * 32 + ni * 16 + (l & 15);
#pragma unroll
      for (int r = 0; r < 4; r++)
        xw1b[(size_t)(row + r) * NHID + col] = f2b(acc[mi][ni][r]);
    }
}

// ---------------- SpMM1: h = bf16(relu(A * xw1 + b1)) ----------------
// Full-row gather: lane covers 4 feats (f0 = lane*4); 64 lanes x uint2 = 256
// feats per wave-gather -> ONE gather per edge. 4 nodes/block, 2500 blocks.

__global__ __launch_bounds__(256) void spmm1_k(const int* __restrict__ cnt,
                                               const int2* __restrict__ epk,
                                               const unsigned short* __restrict__ xw1b,
                                               const float* __restrict__ b1,
                                               unsigned short* __restrict__ h) {
  int wave = threadIdx.x >> 6;
  int lane = threadIdx.x & 63;
  int node = blockIdx.x * 4 + wave;
  int f0   = lane * 4;

  int e0 = node * SLOT;
  int n  = cnt[node << 4];
  float a0 = 0.f, a1 = 0.f, a2 = 0.f, a3 = 0.f;
  for (int base = 0; base < n; base += 64) {
    int c2 = n - base; if (c2 > 64) c2 = 64;
    int2 my = make_int2(0, 0);
    if (lane < c2) my = epk[e0 + base + lane];
    int j = 0;
    for (; j + 8 <= c2; j += 8) {
#pragma unroll
      for (int p = 0; p < 8; p++) {
        int   s  = __shfl(my.x, j + p);
        float wj = __int_as_float(__shfl(my.y, j + p));
        uint2 v = *(const uint2*)&xw1b[(size_t)s * NHID + f0];
        a0 = fmaf(wj, b2f((unsigned short)(v.x & 0xffff)), a0);
        a1 = fmaf(wj, b2f((unsigned short)(v.x >> 16)),    a1);
        a2 = fmaf(wj, b2f((unsigned short)(v.y & 0xffff)), a2);
        a3 = fmaf(wj, b2f((unsigned short)(v.y >> 16)),    a3);
      }
    }
    for (; j < c2; j++) {
      int   s  = __shfl(my.x, j);
      float wj = __int_as_float(__shfl(my.y, j));
      uint2 v = *(const uint2*)&xw1b[(size_t)s * NHID + f0];
      a0 = fmaf(wj, b2f((unsigned short)(v.x & 0xffff)), a0);
      a1 = fmaf(wj, b2f((unsigned short)(v.x >> 16)),    a1);
      a2 = fmaf(wj, b2f((unsigned short)(v.y & 0xffff)), a2);
      a3 = fmaf(wj, b2f((unsigned short)(v.y >> 16)),    a3);
    }
  }
  float4 bb = *(const float4*)&b1[f0];
  a0 = fmaxf(a0 + bb.x, 0.f);
  a1 = fmaxf(a1 + bb.y, 0.f);
  a2 = fmaxf(a2 + bb.z, 0.f);
  a3 = fmaxf(a3 + bb.w, 0.f);
  uint2 po;
  po.x = ((unsigned)f2b(a1) << 16) | f2b(a0);
  po.y = ((unsigned)f2b(a3) << 16) | f2b(a2);
  *(uint2*)&h[(size_t)node * NHID + f0] = po;
}

// ---------------- GEMM2: hw2 = h @ W2  via MFMA, 64x64 tile, K=256 ----------------

__global__ __launch_bounds__(256) void gemm2_k(const unsigned short* __restrict__ h,
                                               const unsigned short* __restrict__ w2t,
                                               float* __restrict__ hw2) {
  __shared__ short8 As[64 * 4];
  __shared__ short8 Bs[64 * 4];

  const int t  = threadIdx.x;
  const int bm = blockIdx.x * 64;
  const int l  = t & 63;
  const int wv = t >> 6;
  const int wr = wv >> 1, wc = wv & 1;
  const int srow = t >> 2, sslot = t & 3;

  const floatx4 zero = {0.f, 0.f, 0.f, 0.f};
  floatx4 acc[2][2];
  acc[0][0] = zero; acc[0][1] = zero; acc[1][0] = zero; acc[1][1] = zero;

  const int q = l >> 4;

  for (int k0 = 0; k0 < NHID; k0 += 32) {
    short8 av = *(const short8*)&h  [(size_t)(bm + srow) * NHID + k0 + sslot * 8];
    short8 bv = *(const short8*)&w2t[(size_t)srow * NHID + k0 + sslot * 8];
    __syncthreads();
    As[srow * 4 + (sslot ^ (srow & 3))] = av;
    Bs[srow * 4 + (sslot ^ (srow & 3))] = bv;
    __syncthreads();

    short8 af[2], bf2[2];
#pragma unroll
    for (int mi = 0; mi < 2; mi++) {
      int ar = wr * 32 + mi * 16 + (l & 15);
      af[mi] = As[ar * 4 + (q ^ (ar & 3))];
    }
#pragma unroll
    for (int ni = 0; ni < 2; ni++) {
      int bc = wc * 32 + ni * 16 + (l & 15);
      bf2[ni] = Bs[bc * 4 + (q ^ (bc & 3))];
    }
#pragma unroll
    for (int mi = 0; mi < 2; mi++)
#pragma unroll
      for (int ni = 0; ni < 2; ni++)
        acc[mi][ni] = __builtin_amdgcn_mfma_f32_16x16x32_bf16(af[mi], bf2[ni], acc[mi][ni], 0, 0, 0);
  }

#pragma unroll
  for (int mi = 0; mi < 2; mi++)
#pragma unroll
    for (int ni = 0; ni < 2; ni++) {
      int row = bm + wr * 32 + mi * 16 + (l >> 4) * 4;
      int col = wc * 32 + ni * 16 + (l & 15);
#pragma unroll
      for (int r = 0; r < 4; r++)
        hw2[(size_t)(row + r) * 64 + col] = acc[mi][ni][r];
    }
}

// ---------------- SpMM2 + b2 + log_softmax -> out ----------------

__global__ __launch_bounds__(256) void spmm2_k(const int* __restrict__ cnt,
                                               const int2* __restrict__ epk,
                                               const float* __restrict__ hw2,
                                               const float* __restrict__ b2,
                                               float* __restrict__ out) {
  int wave = threadIdx.x >> 6;
  int lane = threadIdx.x & 63;
  int i    = blockIdx.x * 4 + wave;
  int hh   = lane >> 5;
  int c    = lane & 31;                 // classes c*2, c*2+1
  bool act = (c * 2 < NCLASS);          // c < 20
  int e0 = i * SLOT;
  int n  = cnt[i << 4];
  float a0 = 0.f, a1 = 0.f;
  for (int base = 0; base < n; base += 64) {
    int c2 = n - base; if (c2 > 64) c2 = 64;
    int2 my = make_int2(0, 0);
    if (lane < c2) my = epk[e0 + base + lane];
    int j = 0;
    for (; j + 8 <= c2; j += 8) {
#pragma unroll
      for (int p = 0; p < 4; p++) {
        int   idx = j + 2 * p + hh;
        int   s   = __shfl(my.x, idx);
        float wj  = __int_as_float(__shfl(my.y, idx));
        float2 v = *(const float2*)&hw2[(size_t)s * 64 + c * 2];
        a0 = fmaf(wj, v.x, a0);
        a1 = fmaf(wj, v.y, a1);
      }
    }
    for (; j < c2; j++) {
      int   s  = __shfl(my.x, j);
      float wj = __int_as_float(__shfl(my.y, j));
      if (hh == 0) {
        float2 v = *(const float2*)&hw2[(size_t)s * 64 + c * 2];
        a0 = fmaf(wj, v.x, a0);
        a1 = fmaf(wj, v.y, a1);
      }
    }
  }
  a0 += __shfl_xor(a0, 32);
  a1 += __shfl_xor(a1, 32);
  if (act) { a0 += b2[c * 2]; a1 += b2[c * 2 + 1]; }
  float mv = act ? fmaxf(a0, a1) : -INFINITY;
#pragma unroll
  for (int o = 16; o > 0; o >>= 1) mv = fmaxf(mv, __shfl_xor(mv, o));
  float ex = act ? (expf(a0 - mv) + expf(a1 - mv)) : 0.f;
#pragma unroll
  for (int o = 16; o > 0; o >>= 1) ex += __shfl_xor(ex, o);
  float ls = logf(ex);
  if (act && hh == 0) {
    float2 o2; o2.x = a0 - mv - ls; o2.y = a1 - mv - ls;
    *(float2*)&out[(size_t)i * NCLASS + c * 2] = o2;
  }
}

// ---------------- launcher ----------------

static inline size_t align256(size_t v) { return (v + 255) & ~(size_t)255; }

extern "C" void kernel_launch(void* const* d_in, const int* in_sizes, int n_in,
                              void* d_out, int out_size, void* d_ws, size_t ws_size,
                              hipStream_t stream) {
  const float* x        = (const float*)d_in[0];
  const int*   edge_src = (const int*)  d_in[1];
  const int*   edge_dst = (const int*)  d_in[2];
  const float* edge_w   = (const float*)d_in[3];
  const float* W1       = (const float*)d_in[4];
  const float* b1       = (const float*)d_in[5];
  const float* W2       = (const float*)d_in[6];
  const float* b2       = (const float*)d_in[7];
  float* out = (float*)d_out;

  char* ws = (char*)d_ws;
  size_t off = 0;
  unsigned short* w1t  = (unsigned short*)(ws + off); off = align256(off + (size_t)NFEAT * NHID * 2);
  unsigned short* w2t  = (unsigned short*)(ws + off); off = align256(off + (size_t)64 * NHID * 2);
  unsigned short* xw1b = (unsigned short*)(ws + off); off = align256(off + (size_t)MPAD * NHID * 2);
  unsigned short* h    = (unsigned short*)(ws + off); off = align256(off + (size_t)MPAD * NHID * 2);
  float* hw2 = (float*)(ws + off); off = align256(off + (size_t)MPAD * 64 * 4);
  int*   cnt = (int*)  (ws + off); off = align256(off + (size_t)N_NODES * CSTRIDE * 4);
  int2*  epk = (int2*) (ws + off); off = align256(off + (size_t)N_NODES * SLOT * 8);

  const int PREP_ITEMS = N_NODES * CSTRIDE;   // 160000 >= weight items
  prep_k<<<(PREP_ITEMS + 255) / 256, 256, 0, stream>>>(W1, W2, w1t, w2t, cnt);

  gemm1_scatter_k<<<NBM1 + EB2, 512, 0, stream>>>(x, w1t, xw1b,
                                                  edge_src, edge_dst, edge_w, cnt, epk);

  spmm1_k<<<2500, 256, 0, stream>>>(cnt, epk, xw1b, b1, h);

  gemm2_k<<<157, 256, 0, stream>>>(h, w2t, hw2);

  spmm2_k<<<2500, 256, 0, stream>>>(cnt, epk, hw2, b2, out);
}